// Round 18
// baseline (98.430 us; speedup 1.0000x reference)
//
#include <hip/hip_runtime.h>

#define BATCH 512
#define DIM   256
#define UNITS 256

typedef __bf16 bf16x8 __attribute__((ext_vector_type(8)));
typedef float  f32x4  __attribute__((ext_vector_type(4)));

__device__ __forceinline__ bf16x8 ld_bf8(const unsigned short* p) {
    uint4 u = *reinterpret_cast<const uint4*>(p);
    return __builtin_bit_cast(bf16x8, u);
}

__device__ __forceinline__ unsigned short bfc(float f) {
    return __builtin_bit_cast(unsigned short, (__bf16)f);
}

__device__ __forceinline__ bf16x8 cvt8(float4 a, float4 b) {
    bf16x8 r;
    r[0] = (__bf16)a.x; r[1] = (__bf16)a.y; r[2] = (__bf16)a.z; r[3] = (__bf16)a.w;
    r[4] = (__bf16)b.x; r[5] = (__bf16)b.y; r[6] = (__bf16)b.z; r[7] = (__bf16)b.w;
    return r;
}

// async 16B global -> LDS (linear dest: wave-uniform base + lane*16)
__device__ __forceinline__ void gload16(void* lds, const void* g) {
    __builtin_amdgcn_global_load_lds(
        (const __attribute__((address_space(1))) unsigned int*)g,
        (__attribute__((address_space(3))) unsigned int*)lds, 16, 0, 0);
}

// Prep (light): s_b = x.x + tr(Sigma_b), softplus table, Wt2 build.
__global__ __launch_bounds__(256) void prep_kernel(
    const float* __restrict__ mu_in, const float* __restrict__ Sigma,
    const float* __restrict__ W, const float* __restrict__ w_sigma,
    unsigned short* __restrict__ Wt2, float* __restrict__ sb,
    float* __restrict__ sp)
{
    const int b = blockIdx.x;
    const int t = threadIdx.x;

    const float xv  = mu_in[b * DIM + t];
    float val = xv * xv + Sigma[(size_t)b * DIM * DIM + (size_t)t * (DIM + 1)];
#pragma unroll
    for (int o = 32; o > 0; o >>= 1) val += __shfl_down(val, o);
    __shared__ float wsum[4];
    if ((t & 63) == 0) wsum[t >> 6] = val;
    __syncthreads();
    if (t == 0) sb[b] = wsum[0] + wsum[1] + wsum[2] + wsum[3];

    if (b < UNITS) {
        const int u   = b;
        const int idx = ((u >> 4) * 8 + (t >> 5)) * 512 + ((t >> 3) & 3) * 128
                      + (u & 15) * 8 + (t & 7);
        Wt2[idx] = bfc(W[t * UNITS + u]);
    }
    if (b == 0) sp[t] = log1pf(expf(w_sigma[t]));
}

// Main: one block per (batch b, 128-col v-half). 512 threads = 8 waves.
// R17 structure + nontemporal output stores (L3 retention for Sigma) +
// setprio around stage-1 MFMA cluster (cross-block arbitration).
__global__ __launch_bounds__(512, 4) void sigma_kernel(
    const float* __restrict__ Sigma, const unsigned short* __restrict__ Wt2,
    const float* __restrict__ sb, const float* __restrict__ sp,
    const float* __restrict__ mu_in, const float* __restrict__ W,
    float* __restrict__ mu_out, float* __restrict__ out)
{
    __shared__ __align__(1024) char smem[81920];
    auto Pt = reinterpret_cast<unsigned short (*)[264]>(smem);
    char* bsh = smem + 65536;

    const int bid     = blockIdx.x;
    const int logical = (bid & 7) * 128 + (bid >> 3);   // XCD-chunked, bijective
    const int b       = logical >> 1;
    const int h       = logical & 1;
    const int v0      = h * 128;
    const int s8      = h * 8;

    const int tid  = threadIdx.x;
    const int lane = tid & 63;
    const int w    = tid >> 6;
    const int lq   = lane >> 4;
    const int lr   = lane & 15;
    const int m0   = w * 32;

    const float* S = Sigma + (size_t)b * DIM * DIM;
    float*       O = out   + (size_t)b * UNITS * UNITS;
    const float  sbv = sb[b];

    const int rsub = lane >> 3;
    const int csrc = (lane & 7) ^ rsub;
    const char* gbase = (const char*)S + (size_t)(w * 32 + rsub) * 1024 + csrc * 16;
    const int   ldsw  = w * 4096;

    const unsigned short* wslab = Wt2 + (size_t)(s8 + w) * 8 * 512;

    const int h7 = lr & 7;
    const int a0r = (m0 + lr) * 128;
    const int a1r = (m0 + 16 + lr) * 128;
    const int c0  = ((2 * lq + 0) ^ h7) * 16;
    const int c1  = ((2 * lq + 1) ^ h7) * 16;

    f32x4 acc[2][8];
#pragma unroll
    for (int i = 0; i < 2; ++i)
#pragma unroll
        for (int j = 0; j < 8; ++j)
#pragma unroll
            for (int r = 0; r < 4; ++r) acc[i][j][r] = 0.f;

    // ---- prologue: slab first (cross-wave data lands earliest), then Sigma
    gload16(bsh + w * 1024, wslab);
#pragma unroll
    for (int q = 0; q < 4; ++q)
        gload16(smem + ldsw + q * 1024, gbase + q * 8192);
    __syncthreads();

    // ---- Stage 1: P[d][v] = sum_e Sigma[d][e] * W[e][v] ----
#pragma unroll
    for (int kk = 0; kk < 8; ++kk) {
        const int cur  = (kk & 1) * 32768;
        char*     bcur = bsh + (kk & 1) * 8192;

        if (kk < 7) {
            const int nxt = cur ^ 32768;
            gload16(bsh + ((kk + 1) & 1) * 8192 + w * 1024, wslab + (kk + 1) * 512);
#pragma unroll
            for (int q = 0; q < 4; ++q)
                gload16(smem + nxt + ldsw + q * 1024,
                        gbase + q * 8192 + (kk + 1) * 128);
        }

        float4 fa0 = *reinterpret_cast<const float4*>(smem + cur + a0r + c0);
        float4 fb0 = *reinterpret_cast<const float4*>(smem + cur + a0r + c1);
        float4 fa1 = *reinterpret_cast<const float4*>(smem + cur + a1r + c0);
        float4 fb1 = *reinterpret_cast<const float4*>(smem + cur + a1r + c1);
        bf16x8 af0 = cvt8(fa0, fb0);
        bf16x8 af1 = cvt8(fa1, fb1);

        __builtin_amdgcn_s_setprio(1);
#pragma unroll
        for (int j = 0; j < 8; ++j) {
            bf16x8 bf = *reinterpret_cast<const bf16x8*>(bcur + j * 1024 + lane * 16);
            acc[0][j] = __builtin_amdgcn_mfma_f32_16x16x32_bf16(af0, bf, acc[0][j], 0, 0, 0);
            acc[1][j] = __builtin_amdgcn_mfma_f32_16x16x32_bf16(af1, bf, acc[1][j], 0, 0, 0);
        }
        __builtin_amdgcn_s_setprio(0);

        __syncthreads();   // full drain: keeps sibling blocks L2-paced
    }

    // ---- write P^T into LDS ----
#pragma unroll
    for (int i = 0; i < 2; ++i) {
#pragma unroll
        for (int j = 0; j < 8; ++j) {
            const int d0 = m0 + 16 * i + 4 * lq;
            const int vl = 16 * j + lr;
            uint2 pk;
            pk.x = (unsigned)bfc(acc[i][j][0]) | ((unsigned)bfc(acc[i][j][1]) << 16);
            pk.y = (unsigned)bfc(acc[i][j][2]) | ((unsigned)bfc(acc[i][j][3]) << 16);
            *reinterpret_cast<uint2*>(&Pt[vl][d0]) = pk;
        }
    }
    __syncthreads();

    // ---- Stage 2: SWAPPED operands -> D[v][u]; Wt2 frags software-pipelined
#pragma unroll
    for (int i = 0; i < 2; ++i)
#pragma unroll
        for (int j = 0; j < 8; ++j)
#pragma unroll
            for (int r = 0; r < 4; ++r) acc[i][j][r] = 0.f;

    const unsigned short* wu0 = Wt2 + (size_t)((w * 2 + 0) * 8) * 512 + lane * 8;
    const unsigned short* wu1 = Wt2 + (size_t)((w * 2 + 1) * 8) * 512 + lane * 8;

    __builtin_amdgcn_s_setprio(1);
    {
        bf16x8 nf0 = ld_bf8(wu0);
        bf16x8 nf1 = ld_bf8(wu1);
#pragma unroll
        for (int kk = 0; kk < 8; ++kk) {
            bf16x8 af0 = nf0, af1 = nf1;
            if (kk < 7) {
                nf0 = ld_bf8(wu0 + (size_t)(kk + 1) * 512);
                nf1 = ld_bf8(wu1 + (size_t)(kk + 1) * 512);
            }
#pragma unroll
            for (int j = 0; j < 8; ++j) {
                bf16x8 pb = *reinterpret_cast<const bf16x8*>(&Pt[16 * j + lr][kk * 32 + 8 * lq]);
                acc[0][j] = __builtin_amdgcn_mfma_f32_16x16x32_bf16(pb, af0, acc[0][j], 0, 0, 0);
                acc[1][j] = __builtin_amdgcn_mfma_f32_16x16x32_bf16(pb, af1, acc[1][j], 0, 0, 0);
            }
        }
    }
    __builtin_amdgcn_s_setprio(0);

    // ---- Epilogue: preload sp, fixup, NONTEMPORAL coalesced stores ----
    f32x4 spv[8];
#pragma unroll
    for (int j = 0; j < 8; ++j)
        spv[j] = *reinterpret_cast<const f32x4*>(&sp[v0 + 16 * j + 4 * lq]);

#pragma unroll
    for (int i = 0; i < 2; ++i) {
        const int u = m0 + 16 * i + lr;
#pragma unroll
        for (int j = 0; j < 8; ++j) {
            const int vb = v0 + 16 * j + 4 * lq;
            f32x4 val = acc[i][j];
#pragma unroll
            for (int r = 0; r < 4; ++r) {
                float x = val[r];
                if (u == vb + r) x += sbv * spv[j][r];
                x = __builtin_isfinite(x) ? x : 0.0f;
                if (u == vb + r) x = fabsf(x);
                val[r] = x;
            }
            __builtin_nontemporal_store(val,
                reinterpret_cast<f32x4*>(&O[(size_t)u * UNITS + vb]));
        }
    }

    // ---- h==0 tail: mu_out[b] = mu_in[b] @ W ----
    if (h == 0) {
        __syncthreads();
        if (tid < 64)
            *reinterpret_cast<float4*>(smem + 69632 + tid * 16) =
                *reinterpret_cast<const float4*>(
                    (const char*)mu_in + (size_t)b * 1024 + tid * 16);
        __syncthreads();

        const int u    = tid & 255;
        const int half = tid >> 8;
        const float* mr = reinterpret_cast<const float*>(smem + 69632) + half * 128;
        const float* Wp = W + (size_t)(half * 128) * UNITS + u;
        float m = 0.f;
#pragma unroll 8
        for (int d = 0; d < 128; ++d) m += mr[d] * Wp[(size_t)d * UNITS];
        reinterpret_cast<float*>(smem)[half * 256 + u] = m;
        __syncthreads();
        if (tid < 256)
            __builtin_nontemporal_store(
                reinterpret_cast<float*>(smem)[tid] +
                reinterpret_cast<float*>(smem)[256 + tid],
                &mu_out[(size_t)b * UNITS + tid]);
    }
}

extern "C" void kernel_launch(void* const* d_in, const int* in_sizes, int n_in,
                              void* d_out, int out_size, void* d_ws, size_t ws_size,
                              hipStream_t stream) {
    const float* mu_in  = (const float*)d_in[0];
    const float* Sigma  = (const float*)d_in[1];
    const float* w_mu   = (const float*)d_in[2];
    const float* w_sig  = (const float*)d_in[3];

    float* mu_out  = (float*)d_out;
    float* Sig_out = (float*)d_out + BATCH * UNITS;

    unsigned short* Wt2 = (unsigned short*)d_ws;                      // 131072 B
    float* sb = (float*)((char*)d_ws + (size_t)DIM * UNITS * 2);      // 512 f32
    float* sp = sb + BATCH;                                           // 256 f32

    prep_kernel<<<BATCH, 256, 0, stream>>>(mu_in, Sigma, w_mu, w_sig, Wt2, sb, sp);
    sigma_kernel<<<BATCH * 2, 512, 0, stream>>>(Sigma, Wt2, sb, sp,
                                                mu_in, w_mu, mu_out, Sig_out);
}

// Round 19
// 70.490 us; speedup vs baseline: 1.3964x; 1.3964x over previous
//
#include <hip/hip_runtime.h>

#define BATCH 512
#define DIM   256
#define UNITS 256

typedef __bf16 bf16x8 __attribute__((ext_vector_type(8)));
typedef float  f32x4  __attribute__((ext_vector_type(4)));

__device__ __forceinline__ bf16x8 ld_bf8(const unsigned short* p) {
    uint4 u = *reinterpret_cast<const uint4*>(p);
    return __builtin_bit_cast(bf16x8, u);
}

__device__ __forceinline__ unsigned short bfc(float f) {
    return __builtin_bit_cast(unsigned short, (__bf16)f);
}

__device__ __forceinline__ bf16x8 cvt8(float4 a, float4 b) {
    bf16x8 r;
    r[0] = (__bf16)a.x; r[1] = (__bf16)a.y; r[2] = (__bf16)a.z; r[3] = (__bf16)a.w;
    r[4] = (__bf16)b.x; r[5] = (__bf16)b.y; r[6] = (__bf16)b.z; r[7] = (__bf16)b.w;
    return r;
}

// async 16B global -> LDS (linear dest: wave-uniform base + lane*16)
__device__ __forceinline__ void gload16(void* lds, const void* g) {
    __builtin_amdgcn_global_load_lds(
        (const __attribute__((address_space(1))) unsigned int*)g,
        (__attribute__((address_space(3))) unsigned int*)lds, 16, 0, 0);
}

// Prep (light): s_b = x.x + tr(Sigma_b), softplus table, Wt2 build.
// The mu_out matvec lives in sigma_kernel's h==0 tail (overlaps via TLP).
__global__ __launch_bounds__(256) void prep_kernel(
    const float* __restrict__ mu_in, const float* __restrict__ Sigma,
    const float* __restrict__ W, const float* __restrict__ w_sigma,
    unsigned short* __restrict__ Wt2, float* __restrict__ sb,
    float* __restrict__ sp)
{
    const int b = blockIdx.x;
    const int t = threadIdx.x;

    const float xv  = mu_in[b * DIM + t];
    float val = xv * xv + Sigma[(size_t)b * DIM * DIM + (size_t)t * (DIM + 1)];
#pragma unroll
    for (int o = 32; o > 0; o >>= 1) val += __shfl_down(val, o);
    __shared__ float wsum[4];
    if ((t & 63) == 0) wsum[t >> 6] = val;
    __syncthreads();
    if (t == 0) sb[b] = wsum[0] + wsum[1] + wsum[2] + wsum[3];

    if (b < UNITS) {
        const int u   = b;
        const int idx = ((u >> 4) * 8 + (t >> 5)) * 512 + ((t >> 3) & 3) * 128
                      + (u & 15) * 8 + (t & 7);
        Wt2[idx] = bfc(W[t * UNITS + u]);
    }
    if (b == 0) sp[t] = log1pf(expf(w_sigma[t]));
}

// Main: one block per (batch b, 128-col v-half). 512 threads = 8 waves.
// Full-drain K-loop (__syncthreads per iter — the only discipline that
// keeps sibling-block Σ L2-sharing + output write-merging intact; counted
// vmcnt and nt-stores both inflate HBM traffic 30-100 MB, measured 5x).
// Slab dedup (Wt2 staged once per block), swapped stage-2 operands ->
// coalesced full-line stores, setprio on stage 2, mu_out fused as h==0 tail.
__global__ __launch_bounds__(512, 4) void sigma_kernel(
    const float* __restrict__ Sigma, const unsigned short* __restrict__ Wt2,
    const float* __restrict__ sb, const float* __restrict__ sp,
    const float* __restrict__ mu_in, const float* __restrict__ W,
    float* __restrict__ mu_out, float* __restrict__ out)
{
    __shared__ __align__(1024) char smem[81920];
    auto Pt = reinterpret_cast<unsigned short (*)[264]>(smem);
    char* bsh = smem + 65536;

    const int bid     = blockIdx.x;
    const int logical = (bid & 7) * 128 + (bid >> 3);   // XCD-chunked, bijective
    const int b       = logical >> 1;
    const int h       = logical & 1;
    const int v0      = h * 128;
    const int s8      = h * 8;

    const int tid  = threadIdx.x;
    const int lane = tid & 63;
    const int w    = tid >> 6;
    const int lq   = lane >> 4;
    const int lr   = lane & 15;
    const int m0   = w * 32;

    const float* S = Sigma + (size_t)b * DIM * DIM;
    float*       O = out   + (size_t)b * UNITS * UNITS;
    const float  sbv = sb[b];

    const int rsub = lane >> 3;
    const int csrc = (lane & 7) ^ rsub;
    const char* gbase = (const char*)S + (size_t)(w * 32 + rsub) * 1024 + csrc * 16;
    const int   ldsw  = w * 4096;

    const unsigned short* wslab = Wt2 + (size_t)(s8 + w) * 8 * 512;

    const int h7 = lr & 7;
    const int a0r = (m0 + lr) * 128;
    const int a1r = (m0 + 16 + lr) * 128;
    const int c0  = ((2 * lq + 0) ^ h7) * 16;
    const int c1  = ((2 * lq + 1) ^ h7) * 16;

    f32x4 acc[2][8];
#pragma unroll
    for (int i = 0; i < 2; ++i)
#pragma unroll
        for (int j = 0; j < 8; ++j)
#pragma unroll
            for (int r = 0; r < 4; ++r) acc[i][j][r] = 0.f;

    // ---- prologue: slab first (cross-wave data lands earliest), then Sigma
    gload16(bsh + w * 1024, wslab);
#pragma unroll
    for (int q = 0; q < 4; ++q)
        gload16(smem + ldsw + q * 1024, gbase + q * 8192);
    __syncthreads();

    // ---- Stage 1: P[d][v] = sum_e Sigma[d][e] * W[e][v] ----
#pragma unroll
    for (int kk = 0; kk < 8; ++kk) {
        const int cur  = (kk & 1) * 32768;
        char*     bcur = bsh + (kk & 1) * 8192;

        if (kk < 7) {
            const int nxt = cur ^ 32768;
            gload16(bsh + ((kk + 1) & 1) * 8192 + w * 1024, wslab + (kk + 1) * 512);
#pragma unroll
            for (int q = 0; q < 4; ++q)
                gload16(smem + nxt + ldsw + q * 1024,
                        gbase + q * 8192 + (kk + 1) * 128);
        }

        float4 fa0 = *reinterpret_cast<const float4*>(smem + cur + a0r + c0);
        float4 fb0 = *reinterpret_cast<const float4*>(smem + cur + a0r + c1);
        float4 fa1 = *reinterpret_cast<const float4*>(smem + cur + a1r + c0);
        float4 fb1 = *reinterpret_cast<const float4*>(smem + cur + a1r + c1);
        bf16x8 af0 = cvt8(fa0, fb0);
        bf16x8 af1 = cvt8(fa1, fb1);

#pragma unroll
        for (int j = 0; j < 8; ++j) {
            bf16x8 bf = *reinterpret_cast<const bf16x8*>(bcur + j * 1024 + lane * 16);
            acc[0][j] = __builtin_amdgcn_mfma_f32_16x16x32_bf16(af0, bf, acc[0][j], 0, 0, 0);
            acc[1][j] = __builtin_amdgcn_mfma_f32_16x16x32_bf16(af1, bf, acc[1][j], 0, 0, 0);
        }

        __syncthreads();   // full drain: keeps sibling blocks L2-paced
    }

    // ---- write P^T into LDS ----
#pragma unroll
    for (int i = 0; i < 2; ++i) {
#pragma unroll
        for (int j = 0; j < 8; ++j) {
            const int d0 = m0 + 16 * i + 4 * lq;
            const int vl = 16 * j + lr;
            uint2 pk;
            pk.x = (unsigned)bfc(acc[i][j][0]) | ((unsigned)bfc(acc[i][j][1]) << 16);
            pk.y = (unsigned)bfc(acc[i][j][2]) | ((unsigned)bfc(acc[i][j][3]) << 16);
            *reinterpret_cast<uint2*>(&Pt[vl][d0]) = pk;
        }
    }
    __syncthreads();

    // ---- Stage 2: SWAPPED operands -> D[v][u]; Wt2 frags software-pipelined
#pragma unroll
    for (int i = 0; i < 2; ++i)
#pragma unroll
        for (int j = 0; j < 8; ++j)
#pragma unroll
            for (int r = 0; r < 4; ++r) acc[i][j][r] = 0.f;

    const unsigned short* wu0 = Wt2 + (size_t)((w * 2 + 0) * 8) * 512 + lane * 8;
    const unsigned short* wu1 = Wt2 + (size_t)((w * 2 + 1) * 8) * 512 + lane * 8;

    __builtin_amdgcn_s_setprio(1);
    {
        bf16x8 nf0 = ld_bf8(wu0);
        bf16x8 nf1 = ld_bf8(wu1);
#pragma unroll
        for (int kk = 0; kk < 8; ++kk) {
            bf16x8 af0 = nf0, af1 = nf1;
            if (kk < 7) {
                nf0 = ld_bf8(wu0 + (size_t)(kk + 1) * 512);
                nf1 = ld_bf8(wu1 + (size_t)(kk + 1) * 512);
            }
#pragma unroll
            for (int j = 0; j < 8; ++j) {
                bf16x8 pb = *reinterpret_cast<const bf16x8*>(&Pt[16 * j + lr][kk * 32 + 8 * lq]);
                acc[0][j] = __builtin_amdgcn_mfma_f32_16x16x32_bf16(pb, af0, acc[0][j], 0, 0, 0);
                acc[1][j] = __builtin_amdgcn_mfma_f32_16x16x32_bf16(pb, af1, acc[1][j], 0, 0, 0);
            }
        }
    }
    __builtin_amdgcn_s_setprio(0);

    // ---- Epilogue: preload sp vectors, then fixup + coalesced stores ----
    f32x4 spv[8];
#pragma unroll
    for (int j = 0; j < 8; ++j)
        spv[j] = *reinterpret_cast<const f32x4*>(&sp[v0 + 16 * j + 4 * lq]);

#pragma unroll
    for (int i = 0; i < 2; ++i) {
        const int u = m0 + 16 * i + lr;
#pragma unroll
        for (int j = 0; j < 8; ++j) {
            const int vb = v0 + 16 * j + 4 * lq;
            f32x4 val = acc[i][j];
#pragma unroll
            for (int r = 0; r < 4; ++r) {
                float x = val[r];
                if (u == vb + r) x += sbv * spv[j][r];
                x = __builtin_isfinite(x) ? x : 0.0f;
                if (u == vb + r) x = fabsf(x);
                val[r] = x;
            }
            *reinterpret_cast<f32x4*>(&O[(size_t)u * UNITS + vb]) = val;
        }
    }

    // ---- h==0 tail: mu_out[b] = mu_in[b] @ W (hidden by sibling blocks'
    // main phases via TLP). 2x128-d partials per u, combined in LDS. ----
    if (h == 0) {
        __syncthreads();   // all waves past their Pt reads before smem reuse
        if (tid < 64)
            *reinterpret_cast<float4*>(smem + 69632 + tid * 16) =
                *reinterpret_cast<const float4*>(
                    (const char*)mu_in + (size_t)b * 1024 + tid * 16);
        __syncthreads();

        const int u    = tid & 255;
        const int half = tid >> 8;
        const float* mr = reinterpret_cast<const float*>(smem + 69632) + half * 128;
        const float* Wp = W + (size_t)(half * 128) * UNITS + u;
        float m = 0.f;
#pragma unroll 8
        for (int d = 0; d < 128; ++d) m += mr[d] * Wp[(size_t)d * UNITS];
        reinterpret_cast<float*>(smem)[half * 256 + u] = m;
        __syncthreads();
        if (tid < 256)
            mu_out[(size_t)b * UNITS + tid] =
                reinterpret_cast<float*>(smem)[tid] +
                reinterpret_cast<float*>(smem)[256 + tid];
    }
}

extern "C" void kernel_launch(void* const* d_in, const int* in_sizes, int n_in,
                              void* d_out, int out_size, void* d_ws, size_t ws_size,
                              hipStream_t stream) {
    const float* mu_in  = (const float*)d_in[0];
    const float* Sigma  = (const float*)d_in[1];
    const float* w_mu   = (const float*)d_in[2];
    const float* w_sig  = (const float*)d_in[3];

    float* mu_out  = (float*)d_out;
    float* Sig_out = (float*)d_out + BATCH * UNITS;

    unsigned short* Wt2 = (unsigned short*)d_ws;                      // 131072 B
    float* sb = (float*)((char*)d_ws + (size_t)DIM * UNITS * 2);      // 512 f32
    float* sp = sb + BATCH;                                           // 256 f32

    prep_kernel<<<BATCH, 256, 0, stream>>>(mu_in, Sigma, w_mu, w_sig, Wt2, sb, sp);
    sigma_kernel<<<BATCH * 2, 512, 0, stream>>>(Sigma, Wt2, sb, sp,
                                                mu_in, w_mu, mu_out, Sig_out);
}